// Round 3
// baseline (1080.420 us; speedup 1.0000x reference)
//
#include <hip/hip_runtime.h>
#include <hip/hip_bf16.h>
#include <math.h>

#define TPB 256

typedef __attribute__((ext_vector_type(8))) __bf16 bf16x8;
typedef __attribute__((ext_vector_type(4))) float f32x4;

// ---- swizzled LDS helpers: byte = row*rowBytes + (byteOff ^ ((row&7)<<4)) ----
static __device__ __forceinline__ bf16x8 lds_frag(const char* base, int row, int byteOff, int rowBytes) {
    return *reinterpret_cast<const bf16x8*>(base + row * rowBytes + (byteOff ^ ((row & 7) << 4)));
}
static __device__ __forceinline__ void lds_wr_bf16(char* base, int row, int col, int rowBytes, float v) {
    *reinterpret_cast<__bf16*>(base + row * rowBytes + ((col << 1) ^ ((row & 7) << 4))) = (__bf16)v;
}

// ws layout: bf16 weights then f32 region
//   wqT@0 (scaled 0.25), wkT@16384, wvT@32768, wpT@49152, w1T@65536 [512][128], w2T@131072 [128][512]
//   f32 @ element 196608: bias_pre[8192] (scores C-frag layout), bq_s[128]
__global__ void convert_w(const float* __restrict__ wq, const float* __restrict__ wk,
                          const float* __restrict__ wv, const float* __restrict__ wp,
                          const float* __restrict__ w1, const float* __restrict__ w2,
                          const float* __restrict__ rpb, const float* __restrict__ bq,
                          __bf16* __restrict__ ws)
{
    int g = blockIdx.x * 256 + threadIdx.x;
    if (g < 65536) {
        int which = g >> 14, idx = g & 16383, n = idx >> 7, k = idx & 127;
        const float* W = (which == 0) ? wq : (which == 1) ? wk : (which == 2) ? wv : wp;
        float v = W[k * 128 + n];
        if (which == 0) v *= 0.25f;                 // fold score scale into wq
        ws[g] = (__bf16)v;
    } else if (g < 131072) {
        int idx = g - 65536, n = idx >> 7, k = idx & 127;
        ws[g] = (__bf16)w1[k * 512 + n];
    } else if (g < 196608) {
        int idx = g - 131072, n = idx >> 9, k = idx & 511;
        ws[g] = (__bf16)w2[k * 128 + n];
    } else if (g < 204800) {
        // bias_pre[(h*4+ct)*256 + lane*4 + r] = bias(n = kg*8+r, m = ct*16+ar), lane = kg*16+ar
        float* wsf = (float*)(ws + 196608);
        int g2 = g - 196608;
        int hc = g2 >> 8, h = hc >> 2, ct = hc & 3;
        int lane = (g2 >> 2) & 63, kg = lane >> 4, ar = lane & 15, r = g2 & 3;
        int dy = kg - h + 7;
        int dx = r - (ct * 2 + (ar >> 3)) + 7;
        wsf[g2] = rpb[(dy * 15 + dx) * 8 + (ar & 7)];
    } else if (g < 204928) {
        float* wsf = (float*)(ws + 196608);
        wsf[8192 + (g - 204800)] = bq[g - 204800] * 0.25f;
    }
}

// LDS offsets (bytes) for attn kernel
#define O_K     0        // bf16 [64][128] swz, rowB 256
#define O_VT    16384    // bf16 [128][64] swz, rowB 128
#define O_XN    32768    // phase1: bf16 [64][128] swz
#define O_ATTN  32768    // phase2: bf16 [32][128] swz (row16 = V_mean)
#define O_PROJ  40960    // phase2: f32 [17][132]
#define O_Q     49936    // bf16 [16][128] swz
#define O_P     54032    // bf16 per-wave [16][64] swz, rowB 128 (+w*2048)
#define O_MU    62224
#define O_RS    62480
#define O_GATE  62736
#define O_BASE  62992
#define SMEM_SZ 63248

__global__ __launch_bounds__(TPB, 2) void swin_attn_kernel(
    const float* __restrict__ x,
    const __bf16* __restrict__ wqT,               // pre-scaled by 0.25
    const __bf16* __restrict__ wkT, const float* __restrict__ bk,
    const __bf16* __restrict__ wvT, const float* __restrict__ bv,
    const __bf16* __restrict__ wpT, const float* __restrict__ bp,
    const float* __restrict__ bias_pre, const float* __restrict__ bqs,
    const float* __restrict__ ln1g, const float* __restrict__ ln1b,
    const float* __restrict__ gate,
    float* __restrict__ out)
{
    __shared__ __align__(16) char smem[SMEM_SZ];
    char* s_k    = smem + O_K;
    char* s_vT   = smem + O_VT;
    char* s_xn   = smem + O_XN;
    char* s_attn = smem + O_ATTN;
    float* s_proj = (float*)(smem + O_PROJ);
    char* s_q    = smem + O_Q;
    float* s_mu   = (float*)(smem + O_MU);
    float* s_rs   = (float*)(smem + O_RS);
    float* s_gate = (float*)(smem + O_GATE);
    int*   s_base = (int*)(smem + O_BASE);

    const int tid = threadIdx.x;
    const int blk = blockIdx.x;
    const int b  = blk >> 10;
    const int wh = (blk >> 5) & 31;
    const int ww = blk & 31;

    // ---------- load + LN1 (shift folded into addressing) ----------
    {
        const int row = tid >> 2;
        const int l4  = tid & 3;
        const int si = wh * 8 + (row >> 3), sj = ww * 8 + (row & 7);
        const int oi = (si + 4) & 255, oj = (sj + 4) & 255;
        const int base = ((b * 256 + oi) * 256 + oj) * 128;
        if (l4 == 0) { s_base[row] = base; s_gate[row] = gate[oi * 256 + oj]; }
        const float* xp = x + base + l4 * 32;
        float vals[32];
        float sum = 0.f, sq = 0.f;
#pragma unroll
        for (int i = 0; i < 8; ++i) {
            const float4 v4 = reinterpret_cast<const float4*>(xp)[i];
            vals[4*i+0] = v4.x; vals[4*i+1] = v4.y; vals[4*i+2] = v4.z; vals[4*i+3] = v4.w;
            sum += v4.x + v4.y + v4.z + v4.w;
            sq  += v4.x*v4.x + v4.y*v4.y + v4.z*v4.z + v4.w*v4.w;
        }
        sum += __shfl_xor(sum, 1); sum += __shfl_xor(sum, 2);
        sq  += __shfl_xor(sq , 1); sq  += __shfl_xor(sq , 2);
        const float mu  = sum * (1.f / 128.f);
        const float var = sq * (1.f / 128.f) - mu * mu;
        const float rs  = rsqrtf(var + 1e-5f);
        if (l4 == 0) { s_mu[row] = mu; s_rs[row] = rs; }
#pragma unroll
        for (int j = 0; j < 4; ++j) {
            bf16x8 pk;
#pragma unroll
            for (int e = 0; e < 8; ++e) {
                const int d = l4 * 32 + j * 8 + e;
                pk[e] = (__bf16)((vals[j*8+e] - mu) * rs * ln1g[d] + ln1b[d]);
            }
            const int byteOff = (l4 * 64 + j * 16) ^ ((row & 7) << 4);
            *reinterpret_cast<bf16x8*>(s_xn + row * 256 + byteOff) = pk;
        }
    }
    __syncthreads();

    const int lane = tid & 63, w = tid >> 6;
    const int ar = lane & 15, kg = lane >> 4;

    float vm[2];   // V column-mean (valid on kg==0 lanes)

    // ---------- QKV via MFMA ----------
    {
        // hoist A fragments
        bf16x8 a[4][4];
#pragma unroll
        for (int rt = 0; rt < 4; ++rt)
#pragma unroll
            for (int kc = 0; kc < 4; ++kc)
                a[rt][kc] = lds_frag(s_xn, rt * 16 + ar, kc * 64 + (kg << 4), 256);
        const int nrow = ((ar >> 2) << 3) + (ar & 3);   // unmasked token for packed row ar
        bf16x8 aq[4];
#pragma unroll
        for (int kc = 0; kc < 4; ++kc)
            aq[kc] = lds_frag(s_xn, nrow, kc * 64 + (kg << 4), 256);

        // K (full 64 rows)
#pragma unroll
        for (int ct2 = 0; ct2 < 2; ++ct2) {
            const int brow = (w + ct2 * 4) * 16 + ar;
            bf16x8 bf[4];
#pragma unroll
            for (int kc = 0; kc < 4; ++kc)
                bf[kc] = *reinterpret_cast<const bf16x8*>(wkT + brow * 128 + kc * 32 + (kg << 3));
            const float bb = bk[brow];
#pragma unroll
            for (int rt = 0; rt < 4; ++rt) {
                f32x4 c = {bb, bb, bb, bb};
#pragma unroll
                for (int kc = 0; kc < 4; ++kc)
                    c = __builtin_amdgcn_mfma_f32_16x16x32_bf16(a[rt][kc], bf[kc], c, 0, 0, 0);
#pragma unroll
                for (int r = 0; r < 4; ++r)
                    lds_wr_bf16(s_k, rt*16 + kg*4 + r, brow, 256, c[r]);
            }
        }
        // V (full 64 rows, transposed store) + column-mean accumulation
#pragma unroll
        for (int ct2 = 0; ct2 < 2; ++ct2) {
            const int brow = (w + ct2 * 4) * 16 + ar;
            bf16x8 bf[4];
#pragma unroll
            for (int kc = 0; kc < 4; ++kc)
                bf[kc] = *reinterpret_cast<const bf16x8*>(wvT + brow * 128 + kc * 32 + (kg << 3));
            const float bb = bv[brow];
            float vs = 0.f;
#pragma unroll
            for (int rt = 0; rt < 4; ++rt) {
                f32x4 c = {bb, bb, bb, bb};
#pragma unroll
                for (int kc = 0; kc < 4; ++kc)
                    c = __builtin_amdgcn_mfma_f32_16x16x32_bf16(a[rt][kc], bf[kc], c, 0, 0, 0);
#pragma unroll
                for (int r = 0; r < 4; ++r) {
                    lds_wr_bf16(s_vT, brow, rt*16 + kg*4 + r, 128, c[r]);
                    vs += c[r];
                }
            }
            vs += __shfl_xor(vs, 16); vs += __shfl_xor(vs, 32);
            vm[ct2] = vs * (1.f / 64.f);
        }
        // Q (only 16 unmasked rows), pre-scaled weights
#pragma unroll
        for (int ct2 = 0; ct2 < 2; ++ct2) {
            const int brow = (w + ct2 * 4) * 16 + ar;
            bf16x8 bf[4];
#pragma unroll
            for (int kc = 0; kc < 4; ++kc)
                bf[kc] = *reinterpret_cast<const bf16x8*>(wqT + brow * 128 + kc * 32 + (kg << 3));
            const float bb = bqs[brow];
            f32x4 c = {bb, bb, bb, bb};
#pragma unroll
            for (int kc = 0; kc < 4; ++kc)
                c = __builtin_amdgcn_mfma_f32_16x16x32_bf16(aq[kc], bf[kc], c, 0, 0, 0);
#pragma unroll
            for (int r = 0; r < 4; ++r)
                lds_wr_bf16(s_q, kg*4 + r, brow, 256, c[r]);
        }
    }
    __syncthreads();

    // V_mean -> s_attn row 16 (xn region now dead)
    if (kg == 0) {
#pragma unroll
        for (int ct2 = 0; ct2 < 2; ++ct2)
            lds_wr_bf16(s_attn, 16, (w + ct2 * 4) * 16 + ar, 256, vm[ct2]);
    }

    // ---------- attention: wave w handles heads w and w+4, 16 unmasked rows ----------
    char* s_p = smem + O_P + (w << 11);
#pragma unroll
    for (int hi = 0; hi < 2; ++hi) {
        const int h = w + hi * 4;
        bf16x8 aQ = {};
        if (lane < 32) aQ = lds_frag(s_q, ar, h * 32 + (kg << 4), 256);
        f32x4 sc[4];
#pragma unroll
        for (int ct = 0; ct < 4; ++ct) {
            bf16x8 bK = {};
            if (lane < 32) bK = lds_frag(s_k, ct * 16 + ar, h * 32 + (kg << 4), 256);
            const f32x4 cin = *reinterpret_cast<const f32x4*>(bias_pre + ((h * 4 + ct) << 8) + (lane << 2));
            sc[ct] = __builtin_amdgcn_mfma_f32_16x16x32_bf16(aQ, bK, cin, 0, 0, 0);
        }
        // softmax (scores bounded ~|1|: skip max-subtract; no masked rows here)
        float s[4] = {0.f, 0.f, 0.f, 0.f};
#pragma unroll
        for (int ct = 0; ct < 4; ++ct)
#pragma unroll
            for (int r = 0; r < 4; ++r) {
                sc[ct][r] = __expf(sc[ct][r]);
                s[r] += sc[ct][r];
            }
#pragma unroll
        for (int r = 0; r < 4; ++r) {
            s[r] += __shfl_xor(s[r], 1); s[r] += __shfl_xor(s[r], 2);
            s[r] += __shfl_xor(s[r], 4); s[r] += __shfl_xor(s[r], 8);
            const float inv = 1.f / s[r];
#pragma unroll
            for (int ct = 0; ct < 4; ++ct)
                lds_wr_bf16(s_p, kg*4 + r, ct*16 + ar, 128, sc[ct][r] * inv);
        }
        // PV
        f32x4 o = {0.f, 0.f, 0.f, 0.f};
#pragma unroll
        for (int kc = 0; kc < 2; ++kc) {
            bf16x8 ap = lds_frag(s_p, ar, kc * 64 + (kg << 4), 128);
            bf16x8 bV = lds_frag(s_vT, h * 16 + ar, kc * 64 + (kg << 4), 128);
            o = __builtin_amdgcn_mfma_f32_16x16x32_bf16(ap, bV, o, 0, 0, 0);
        }
#pragma unroll
        for (int r = 0; r < 4; ++r)
            lds_wr_bf16(s_attn, kg*4 + r, h*16 + ar, 256, o[r]);
    }
    __syncthreads();

    // ---------- proj: M=32 (rows 0..15 = unmasked attn-out, row 16 = V_mean) ----------
    {
        bf16x8 a2[2][4];
#pragma unroll
        for (int rt = 0; rt < 2; ++rt)
#pragma unroll
            for (int kc = 0; kc < 4; ++kc)
                a2[rt][kc] = lds_frag(s_attn, rt * 16 + ar, kc * 64 + (kg << 4), 256);
#pragma unroll
        for (int ct2 = 0; ct2 < 2; ++ct2) {
            const int brow = (w + ct2 * 4) * 16 + ar;
            bf16x8 bf[4];
#pragma unroll
            for (int kc = 0; kc < 4; ++kc)
                bf[kc] = *reinterpret_cast<const bf16x8*>(wpT + brow * 128 + kc * 32 + (kg << 3));
            const float bb = bp[brow];
#pragma unroll
            for (int rt = 0; rt < 2; ++rt) {
                f32x4 c = {bb, bb, bb, bb};
#pragma unroll
                for (int kc = 0; kc < 4; ++kc)
                    c = __builtin_amdgcn_mfma_f32_16x16x32_bf16(a2[rt][kc], bf[kc], c, 0, 0, 0);
                if (rt == 0) {
#pragma unroll
                    for (int r = 0; r < 4; ++r)
                        s_proj[(kg*4 + r) * 132 + brow] = c[r];
                } else if (kg == 0) {
                    s_proj[16 * 132 + brow] = c[0];   // row 16 = V_mean proj
                }
            }
        }
    }
    __syncthreads();

    // ---------- assemble: out = xn + proj_row + sigmoid(gate)*x ----------
    {
        const int row = tid >> 2, l4 = tid & 3;
        const int base = s_base[row];
        const float mu = s_mu[row], rs = s_rs[row];
        const float sg = 1.f / (1.f + __expf(-s_gate[row]));
        const bool masked = ((row >> 3) >= 4) || ((row & 7) >= 4);
        const int prow = masked ? 16 : ((row >> 3) * 4 + (row & 7));
        const float* pr = s_proj + prow * 132 + l4 * 32;
        const float* xp = x + base + l4 * 32;
        float* op = out + base + l4 * 32;
        const float* g1 = ln1g + l4 * 32;
        const float* b1v = ln1b + l4 * 32;
#pragma unroll
        for (int i = 0; i < 8; ++i) {
            const float4 v4 = reinterpret_cast<const float4*>(xp)[i];
            const float4 gg = reinterpret_cast<const float4*>(g1)[i];
            const float4 bb = reinterpret_cast<const float4*>(b1v)[i];
            float4 o;
            o.x = (v4.x - mu) * rs * gg.x + bb.x + pr[4*i+0] + sg * v4.x;
            o.y = (v4.y - mu) * rs * gg.y + bb.y + pr[4*i+1] + sg * v4.y;
            o.z = (v4.z - mu) * rs * gg.z + bb.z + pr[4*i+2] + sg * v4.z;
            o.w = (v4.w - mu) * rs * gg.w + bb.w + pr[4*i+3] + sg * v4.w;
            reinterpret_cast<float4*>(op)[i] = o;
        }
    }
}

__global__ __launch_bounds__(TPB, 3) void swin_mlp_kernel(
    const float* __restrict__ ln2g, const float* __restrict__ ln2b,
    const __bf16* __restrict__ w1T, const float* __restrict__ b1,
    const __bf16* __restrict__ w2T, const float* __restrict__ b2,
    float* __restrict__ io)
{
    __shared__ __align__(16) char s_xn[64 * 256];   // bf16 [64][128] swz
    __shared__ __align__(16) char s_h [64 * 512];   // bf16 [64][256] swz (one hidden half)
    const int tid  = threadIdx.x;
    const int base = blockIdx.x * (64 * 128);
    const int lane = tid & 63, w = tid >> 6;
    const int ar = lane & 15, kg = lane >> 4;

    // ---------- LN2 ----------
    {
        const int row = tid >> 2;
        const int l4  = tid & 3;
        const float* xp = io + base + row * 128 + l4 * 32;
        float vals[32];
        float sum = 0.f, sq = 0.f;
#pragma unroll
        for (int i = 0; i < 8; ++i) {
            const float4 v4 = reinterpret_cast<const float4*>(xp)[i];
            vals[4*i+0] = v4.x; vals[4*i+1] = v4.y; vals[4*i+2] = v4.z; vals[4*i+3] = v4.w;
            sum += v4.x + v4.y + v4.z + v4.w;
            sq  += v4.x*v4.x + v4.y*v4.y + v4.z*v4.z + v4.w*v4.w;
        }
        sum += __shfl_xor(sum, 1); sum += __shfl_xor(sum, 2);
        sq  += __shfl_xor(sq , 1); sq  += __shfl_xor(sq , 2);
        const float mu  = sum * (1.f / 128.f);
        const float var = sq * (1.f / 128.f) - mu * mu;
        const float rs  = rsqrtf(var + 1e-5f);
#pragma unroll
        for (int j = 0; j < 4; ++j) {
            bf16x8 pk;
#pragma unroll
            for (int e = 0; e < 8; ++e) {
                const int d = l4 * 32 + j * 8 + e;
                pk[e] = (__bf16)((vals[j*8+e] - mu) * rs * ln2g[d] + ln2b[d]);
            }
            const int byteOff = (l4 * 64 + j * 16) ^ ((row & 7) << 4);
            *reinterpret_cast<bf16x8*>(s_xn + row * 256 + byteOff) = pk;
        }
    }
    __syncthreads();

    // hoist A-frags (xn)
    bf16x8 a[4][4];
#pragma unroll
    for (int rt = 0; rt < 4; ++rt)
#pragma unroll
        for (int kc = 0; kc < 4; ++kc)
            a[rt][kc] = lds_frag(s_xn, rt * 16 + ar, kc * 64 + (kg << 4), 256);

    f32x4 acc2[2][4];
#pragma unroll
    for (int ct2 = 0; ct2 < 2; ++ct2) {
        const float bb = b2[(w + ct2 * 4) * 16 + ar];
#pragma unroll
        for (int rt = 0; rt < 4; ++rt) acc2[ct2][rt] = {bb, bb, bb, bb};
    }

#pragma unroll
    for (int hh = 0; hh < 2; ++hh) {
        // GEMM1 half: h[:, hh*256 .. +256] = gelu(xn @ w1 + b1)
#pragma unroll
        for (int i = 0; i < 4; ++i) {
            const int ct = hh * 16 + w + 4 * i;
            const int brow = ct * 16 + ar;          // hidden col 0..511
            bf16x8 bfr[4];
#pragma unroll
            for (int kc = 0; kc < 4; ++kc)
                bfr[kc] = *reinterpret_cast<const bf16x8*>(w1T + brow * 128 + kc * 32 + (kg << 3));
            const float bb = b1[brow];
#pragma unroll
            for (int rt = 0; rt < 4; ++rt) {
                f32x4 c = {bb, bb, bb, bb};
#pragma unroll
                for (int kc = 0; kc < 4; ++kc)
                    c = __builtin_amdgcn_mfma_f32_16x16x32_bf16(a[rt][kc], bfr[kc], c, 0, 0, 0);
#pragma unroll
                for (int r = 0; r < 4; ++r) {
                    const float v = c[r];
                    const float t = 0.7978845608028654f * (v + 0.044715f * v * v * v);
                    const float th = 1.f - 2.f / (__expf(2.f * t) + 1.f);
                    lds_wr_bf16(s_h, rt * 16 + kg * 4 + r, brow - hh * 256, 512, 0.5f * v * (1.f + th));
                }
            }
        }
        __syncthreads();
        // GEMM2 partial: y += h_half @ w2[hh*256..]
#pragma unroll
        for (int kc = 0; kc < 8; ++kc) {
            bf16x8 ah[4];
#pragma unroll
            for (int rt = 0; rt < 4; ++rt)
                ah[rt] = lds_frag(s_h, rt * 16 + ar, kc * 64 + (kg << 4), 512);
#pragma unroll
            for (int ct2 = 0; ct2 < 2; ++ct2) {
                const int brow = (w + ct2 * 4) * 16 + ar;
                const bf16x8 bw = *reinterpret_cast<const bf16x8*>(w2T + brow * 512 + hh * 256 + kc * 32 + (kg << 3));
#pragma unroll
                for (int rt = 0; rt < 4; ++rt)
                    acc2[ct2][rt] = __builtin_amdgcn_mfma_f32_16x16x32_bf16(ah[rt], bw, acc2[ct2][rt], 0, 0, 0);
            }
        }
        __syncthreads();
    }

    // residual, in-place
#pragma unroll
    for (int ct2 = 0; ct2 < 2; ++ct2)
#pragma unroll
        for (int rt = 0; rt < 4; ++rt)
#pragma unroll
            for (int r = 0; r < 4; ++r) {
                const int n = rt * 16 + kg * 4 + r;
                const int col = (w + ct2 * 4) * 16 + ar;
                const int idx = base + n * 128 + col;
                io[idx] = io[idx] + acc2[ct2][rt][r];
            }
}

extern "C" void kernel_launch(void* const* d_in, const int* in_sizes, int n_in,
                              void* d_out, int out_size, void* d_ws, size_t ws_size,
                              hipStream_t stream) {
    (void)in_sizes; (void)n_in; (void)ws_size; (void)out_size;
    const float* x    = (const float*)d_in[0];
    const float* wq   = (const float*)d_in[1];
    const float* bq   = (const float*)d_in[2];
    const float* wk   = (const float*)d_in[3];
    const float* bk   = (const float*)d_in[4];
    const float* wv   = (const float*)d_in[5];
    const float* bv   = (const float*)d_in[6];
    const float* wp   = (const float*)d_in[7];
    const float* bp   = (const float*)d_in[8];
    const float* rpb  = (const float*)d_in[9];
    const float* ln1g = (const float*)d_in[10];
    const float* ln1b = (const float*)d_in[11];
    const float* ln2g = (const float*)d_in[12];
    const float* ln2b = (const float*)d_in[13];
    const float* w1   = (const float*)d_in[14];
    const float* b1   = (const float*)d_in[15];
    const float* w2   = (const float*)d_in[16];
    const float* b2   = (const float*)d_in[17];
    const float* gate = (const float*)d_in[18];
    float* out = (float*)d_out;

    __bf16* ws = (__bf16*)d_ws;
    const __bf16* wqT = ws;
    const __bf16* wkT = ws + 16384;
    const __bf16* wvT = ws + 32768;
    const __bf16* wpT = ws + 49152;
    const __bf16* w1T = ws + 65536;
    const __bf16* w2T = ws + 131072;
    const float* wsf  = (const float*)(ws + 196608);
    const float* bias_pre = wsf;
    const float* bqs      = wsf + 8192;

    convert_w<<<801, 256, 0, stream>>>(wq, wk, wv, wp, w1, w2, rpb, bq, ws);
    swin_attn_kernel<<<8192, TPB, 0, stream>>>(x, wqT, wkT, bk, wvT, bv, wpT, bp,
                                               bias_pre, bqs, ln1g, ln1b, gate, out);
    swin_mlp_kernel<<<8192, TPB, 0, stream>>>(ln2g, ln2b, w1T, b1, w2T, b2, out);
}

// Round 5
// 701.095 us; speedup vs baseline: 1.5410x; 1.5410x over previous
//
#include <hip/hip_runtime.h>
#include <hip/hip_bf16.h>
#include <math.h>

#define TPB 256

typedef __attribute__((ext_vector_type(8))) __bf16 bf16x8;
typedef __attribute__((ext_vector_type(4))) float f32x4;

// ---- swizzled LDS helpers: byte = row*rowBytes + (byteOff ^ ((row&7)<<4)) ----
static __device__ __forceinline__ bf16x8 lds_frag(const char* base, int row, int byteOff, int rowBytes) {
    return *reinterpret_cast<const bf16x8*>(base + row * rowBytes + (byteOff ^ ((row & 7) << 4)));
}
static __device__ __forceinline__ void lds_wr_bf16(char* base, int row, int col, int rowBytes, float v) {
    *reinterpret_cast<__bf16*>(base + row * rowBytes + ((col << 1) ^ ((row & 7) << 4))) = (__bf16)v;
}

// ws layout: bf16 weights then f32 region
//   wqT@0 (scaled 0.25), wkT@16384, wvT@32768, wpT@49152, w1T@65536 [512][128], w2T@131072 [128][512]
//   f32 @ element 196608: bias_pre[8192] (scores C-frag layout), bq_s[128]
__global__ void convert_w(const float* __restrict__ wq, const float* __restrict__ wk,
                          const float* __restrict__ wv, const float* __restrict__ wp,
                          const float* __restrict__ w1, const float* __restrict__ w2,
                          const float* __restrict__ rpb, const float* __restrict__ bq,
                          __bf16* __restrict__ ws)
{
    int g = blockIdx.x * 256 + threadIdx.x;
    if (g < 65536) {
        int which = g >> 14, idx = g & 16383, n = idx >> 7, k = idx & 127;
        const float* W = (which == 0) ? wq : (which == 1) ? wk : (which == 2) ? wv : wp;
        float v = W[k * 128 + n];
        if (which == 0) v *= 0.25f;                 // fold score scale into wq
        ws[g] = (__bf16)v;
    } else if (g < 131072) {
        int idx = g - 65536, n = idx >> 7, k = idx & 127;
        ws[g] = (__bf16)w1[k * 512 + n];
    } else if (g < 196608) {
        int idx = g - 131072, n = idx >> 9, k = idx & 511;
        ws[g] = (__bf16)w2[k * 128 + n];
    } else if (g < 204800) {
        // bias_pre[(h*4+ct)*256 + lane*4 + r] = bias(n = kg*8+r, m = ct*16+ar), lane = kg*16+ar
        float* wsf = (float*)(ws + 196608);
        int g2 = g - 196608;
        int hc = g2 >> 8, h = hc >> 2, ct = hc & 3;
        int lane = (g2 >> 2) & 63, kg = lane >> 4, ar = lane & 15, r = g2 & 3;
        int dy = kg - h + 7;
        int dx = r - (ct * 2 + (ar >> 3)) + 7;
        wsf[g2] = rpb[(dy * 15 + dx) * 8 + (ar & 7)];
    } else if (g < 204928) {
        float* wsf = (float*)(ws + 196608);
        wsf[8192 + (g - 204800)] = bq[g - 204800] * 0.25f;
    }
}

// LDS offsets (bytes)
#define O_K     0        // bf16 [64][128] swz rowB256: K ; later xn2 (LN2 out)
#define O_VT    16384    // bf16 [128][64] swz rowB128: V^T ; later s_h lower
#define O_XN    32768    // bf16 [64][128] swz rowB256: xn ; later s_h upper
#define O_H     16384    // bf16 [64][256] swz rowB512 (one hidden half)
#define O_ATTN  49152    // bf16 [17][128] swz rowB256: attn-out + V_mean row 16
#define O_PROJ  57344    // f32 [17][132]
#define O_Q     66320    // bf16 [16][128] swz rowB256
#define O_P     70416    // per-wave bf16 [16][64] swz rowB128 (+w*2048)
#define O_MU    78608
#define O_RS    78864
#define O_GATE  79120
#define O_BASE  79376
#define SMEM_SZ 79632
// s_out staging: f32 [64][132] at offset 0 (33792 B), used only after GEMM2

__global__ __launch_bounds__(TPB, 2) void swin_fused_kernel(
    const float* __restrict__ x,
    const __bf16* __restrict__ wqT,               // pre-scaled by 0.25
    const __bf16* __restrict__ wkT, const float* __restrict__ bk,
    const __bf16* __restrict__ wvT, const float* __restrict__ bv,
    const __bf16* __restrict__ wpT, const float* __restrict__ bp,
    const float* __restrict__ bias_pre, const float* __restrict__ bqs,
    const float* __restrict__ ln1g, const float* __restrict__ ln1b,
    const float* __restrict__ ln2g, const float* __restrict__ ln2b,
    const __bf16* __restrict__ w1T, const float* __restrict__ b1,
    const __bf16* __restrict__ w2T, const float* __restrict__ b2,
    const float* __restrict__ gate,
    float* __restrict__ out)
{
    __shared__ __align__(16) char smem[SMEM_SZ];
    char* s_k    = smem + O_K;
    char* s_vT   = smem + O_VT;
    char* s_xn   = smem + O_XN;
    char* s_h    = smem + O_H;
    char* s_attn = smem + O_ATTN;
    float* s_proj = (float*)(smem + O_PROJ);
    char* s_q    = smem + O_Q;
    float* s_out  = (float*)(smem);
    float* s_mu   = (float*)(smem + O_MU);
    float* s_rs   = (float*)(smem + O_RS);
    float* s_gate = (float*)(smem + O_GATE);
    int*   s_base = (int*)(smem + O_BASE);

    const int tid = threadIdx.x;
    const int blk = blockIdx.x;
    const int b  = blk >> 10;
    const int wh = (blk >> 5) & 31;
    const int ww = blk & 31;

    const int row = tid >> 2;     // token row for per-token phases
    const int l4  = tid & 3;
    float vals[32];               // raw x during attn; x2 after assemble

    // ---------- phase 1: load + LN1 (shift folded into addressing) ----------
    {
        const int si = wh * 8 + (row >> 3), sj = ww * 8 + (row & 7);
        const int oi = (si + 4) & 255, oj = (sj + 4) & 255;
        const int base = ((b * 256 + oi) * 256 + oj) * 128;
        if (l4 == 0) { s_base[row] = base; s_gate[row] = gate[oi * 256 + oj]; }
        const float* xp = x + base + l4 * 32;
        float sum = 0.f, sq = 0.f;
#pragma unroll
        for (int i = 0; i < 8; ++i) {
            const float4 v4 = reinterpret_cast<const float4*>(xp)[i];
            vals[4*i+0] = v4.x; vals[4*i+1] = v4.y; vals[4*i+2] = v4.z; vals[4*i+3] = v4.w;
            sum += v4.x + v4.y + v4.z + v4.w;
            sq  += v4.x*v4.x + v4.y*v4.y + v4.z*v4.z + v4.w*v4.w;
        }
        sum += __shfl_xor(sum, 1); sum += __shfl_xor(sum, 2);
        sq  += __shfl_xor(sq , 1); sq  += __shfl_xor(sq , 2);
        const float mu  = sum * (1.f / 128.f);
        const float var = sq * (1.f / 128.f) - mu * mu;
        const float rs  = rsqrtf(var + 1e-5f);
        if (l4 == 0) { s_mu[row] = mu; s_rs[row] = rs; }
#pragma unroll
        for (int j = 0; j < 4; ++j) {
            bf16x8 pk;
#pragma unroll
            for (int e = 0; e < 8; ++e) {
                const int d = l4 * 32 + j * 8 + e;
                pk[e] = (__bf16)((vals[j*8+e] - mu) * rs * ln1g[d] + ln1b[d]);
            }
            const int byteOff = (l4 * 64 + j * 16) ^ ((row & 7) << 4);
            *reinterpret_cast<bf16x8*>(s_xn + row * 256 + byteOff) = pk;
        }
    }
    __syncthreads();

    const int lane = tid & 63, w = tid >> 6;
    const int ar = lane & 15, kg = lane >> 4;

    float vm[2];   // V column-mean (valid on kg==0 lanes)

    // ---------- phase 2: QKV via MFMA ----------
    {
        bf16x8 a[4][4];
#pragma unroll
        for (int rt = 0; rt < 4; ++rt)
#pragma unroll
            for (int kc = 0; kc < 4; ++kc)
                a[rt][kc] = lds_frag(s_xn, rt * 16 + ar, kc * 64 + (kg << 4), 256);
        const int nrow = ((ar >> 2) << 3) + (ar & 3);   // unmasked token for packed row ar
        bf16x8 aq[4];
#pragma unroll
        for (int kc = 0; kc < 4; ++kc)
            aq[kc] = lds_frag(s_xn, nrow, kc * 64 + (kg << 4), 256);

        // K (full 64 rows)
#pragma unroll
        for (int ct2 = 0; ct2 < 2; ++ct2) {
            const int brow = (w + ct2 * 4) * 16 + ar;
            bf16x8 bf[4];
#pragma unroll
            for (int kc = 0; kc < 4; ++kc)
                bf[kc] = *reinterpret_cast<const bf16x8*>(wkT + brow * 128 + kc * 32 + (kg << 3));
            const float bb = bk[brow];
#pragma unroll
            for (int rt = 0; rt < 4; ++rt) {
                f32x4 c = {bb, bb, bb, bb};
#pragma unroll
                for (int kc = 0; kc < 4; ++kc)
                    c = __builtin_amdgcn_mfma_f32_16x16x32_bf16(a[rt][kc], bf[kc], c, 0, 0, 0);
#pragma unroll
                for (int r = 0; r < 4; ++r)
                    lds_wr_bf16(s_k, rt*16 + kg*4 + r, brow, 256, c[r]);
            }
        }
        // V (full 64 rows, transposed store) + column-mean
#pragma unroll
        for (int ct2 = 0; ct2 < 2; ++ct2) {
            const int brow = (w + ct2 * 4) * 16 + ar;
            bf16x8 bf[4];
#pragma unroll
            for (int kc = 0; kc < 4; ++kc)
                bf[kc] = *reinterpret_cast<const bf16x8*>(wvT + brow * 128 + kc * 32 + (kg << 3));
            const float bb = bv[brow];
            float vs = 0.f;
#pragma unroll
            for (int rt = 0; rt < 4; ++rt) {
                f32x4 c = {bb, bb, bb, bb};
#pragma unroll
                for (int kc = 0; kc < 4; ++kc)
                    c = __builtin_amdgcn_mfma_f32_16x16x32_bf16(a[rt][kc], bf[kc], c, 0, 0, 0);
#pragma unroll
                for (int r = 0; r < 4; ++r) {
                    lds_wr_bf16(s_vT, brow, rt*16 + kg*4 + r, 128, c[r]);
                    vs += c[r];
                }
            }
            vs += __shfl_xor(vs, 16); vs += __shfl_xor(vs, 32);
            vm[ct2] = vs * (1.f / 64.f);
        }
        // Q (only 16 unmasked rows), pre-scaled weights
#pragma unroll
        for (int ct2 = 0; ct2 < 2; ++ct2) {
            const int brow = (w + ct2 * 4) * 16 + ar;
            bf16x8 bf[4];
#pragma unroll
            for (int kc = 0; kc < 4; ++kc)
                bf[kc] = *reinterpret_cast<const bf16x8*>(wqT + brow * 128 + kc * 32 + (kg << 3));
            const float bb = bqs[brow];
            f32x4 c = {bb, bb, bb, bb};
#pragma unroll
            for (int kc = 0; kc < 4; ++kc)
                c = __builtin_amdgcn_mfma_f32_16x16x32_bf16(aq[kc], bf[kc], c, 0, 0, 0);
#pragma unroll
            for (int r = 0; r < 4; ++r)
                lds_wr_bf16(s_q, kg*4 + r, brow, 256, c[r]);
        }
    }
    __syncthreads();

    // V_mean -> s_attn row 16
    if (kg == 0) {
#pragma unroll
        for (int ct2 = 0; ct2 < 2; ++ct2)
            lds_wr_bf16(s_attn, 16, (w + ct2 * 4) * 16 + ar, 256, vm[ct2]);
    }

    // ---------- phase 3: attention (wave w: heads w, w+4; 16 unmasked rows) ----------
    char* s_p = smem + O_P + (w << 11);
#pragma unroll
    for (int hi = 0; hi < 2; ++hi) {
        const int h = w + hi * 4;
        bf16x8 aQ = {};
        if (lane < 32) aQ = lds_frag(s_q, ar, h * 32 + (kg << 4), 256);
        f32x4 sc[4];
#pragma unroll
        for (int ct = 0; ct < 4; ++ct) {
            bf16x8 bK = {};
            if (lane < 32) bK = lds_frag(s_k, ct * 16 + ar, h * 32 + (kg << 4), 256);
            const f32x4 cin = *reinterpret_cast<const f32x4*>(bias_pre + ((h * 4 + ct) << 8) + (lane << 2));
            sc[ct] = __builtin_amdgcn_mfma_f32_16x16x32_bf16(aQ, bK, cin, 0, 0, 0);
        }
        float s[4] = {0.f, 0.f, 0.f, 0.f};
#pragma unroll
        for (int ct = 0; ct < 4; ++ct)
#pragma unroll
            for (int r = 0; r < 4; ++r) {
                sc[ct][r] = __expf(sc[ct][r]);
                s[r] += sc[ct][r];
            }
#pragma unroll
        for (int r = 0; r < 4; ++r) {
            s[r] += __shfl_xor(s[r], 1); s[r] += __shfl_xor(s[r], 2);
            s[r] += __shfl_xor(s[r], 4); s[r] += __shfl_xor(s[r], 8);
            const float inv = 1.f / s[r];
#pragma unroll
            for (int ct = 0; ct < 4; ++ct)
                lds_wr_bf16(s_p, kg*4 + r, ct*16 + ar, 128, sc[ct][r] * inv);
        }
        f32x4 o = {0.f, 0.f, 0.f, 0.f};
#pragma unroll
        for (int kc = 0; kc < 2; ++kc) {
            bf16x8 ap = lds_frag(s_p, ar, kc * 64 + (kg << 4), 128);
            bf16x8 bV = lds_frag(s_vT, h * 16 + ar, kc * 64 + (kg << 4), 128);
            o = __builtin_amdgcn_mfma_f32_16x16x32_bf16(ap, bV, o, 0, 0, 0);
        }
#pragma unroll
        for (int r = 0; r < 4; ++r)
            lds_wr_bf16(s_attn, kg*4 + r, h*16 + ar, 256, o[r]);
    }
    __syncthreads();

    // ---------- phase 4: proj (M=17: 16 unmasked rows + V_mean) ----------
    {
        bf16x8 a2[2][4];
#pragma unroll
        for (int rt = 0; rt < 2; ++rt)
#pragma unroll
            for (int kc = 0; kc < 4; ++kc)
                a2[rt][kc] = lds_frag(s_attn, rt * 16 + ar, kc * 64 + (kg << 4), 256);
#pragma unroll
        for (int ct2 = 0; ct2 < 2; ++ct2) {
            const int brow = (w + ct2 * 4) * 16 + ar;
            bf16x8 bf[4];
#pragma unroll
            for (int kc = 0; kc < 4; ++kc)
                bf[kc] = *reinterpret_cast<const bf16x8*>(wpT + brow * 128 + kc * 32 + (kg << 3));
            const float bb = bp[brow];
#pragma unroll
            for (int rt = 0; rt < 2; ++rt) {
                f32x4 c = {bb, bb, bb, bb};
#pragma unroll
                for (int kc = 0; kc < 4; ++kc)
                    c = __builtin_amdgcn_mfma_f32_16x16x32_bf16(a2[rt][kc], bf[kc], c, 0, 0, 0);
                if (rt == 0) {
#pragma unroll
                    for (int r = 0; r < 4; ++r)
                        s_proj[(kg*4 + r) * 132 + brow] = c[r];
                } else if (kg == 0) {
                    s_proj[16 * 132 + brow] = c[0];   // V_mean row
                }
            }
        }
    }
    __syncthreads();

    // ---------- phase 5: assemble x2 (f32 xn recompute, as in R3) + LN2 -> xn2 into O_K ----------
    {
        const float sg = 1.f / (1.f + __expf(-s_gate[row]));
        const float mu1 = s_mu[row], rs1 = s_rs[row];
        const bool masked = ((row >> 3) >= 4) || ((row & 7) >= 4);
        const int prow = masked ? 16 : ((row >> 3) * 4 + (row & 7));
        const float* pr = s_proj + prow * 132 + l4 * 32;
        const float* g1  = ln1g + l4 * 32;
        const float* b1v = ln1b + l4 * 32;
        float sum = 0.f, sq = 0.f;
#pragma unroll
        for (int i = 0; i < 8; ++i) {
            const float4 gg = reinterpret_cast<const float4*>(g1)[i];
            const float4 bb = reinterpret_cast<const float4*>(b1v)[i];
            const float g4[4] = {gg.x, gg.y, gg.z, gg.w};
            const float b4[4] = {bb.x, bb.y, bb.z, bb.w};
#pragma unroll
            for (int c = 0; c < 4; ++c) {
                const int idx = 4*i + c;
                const float xv = vals[idx];
                const float xnv = (xv - mu1) * rs1 * g4[c] + b4[c];
                const float x2 = xnv + pr[idx] + sg * xv;
                vals[idx] = x2;
                sum += x2; sq += x2 * x2;
            }
        }
        sum += __shfl_xor(sum, 1); sum += __shfl_xor(sum, 2);
        sq  += __shfl_xor(sq , 1); sq  += __shfl_xor(sq , 2);
        const float mu  = sum * (1.f / 128.f);
        const float var = sq * (1.f / 128.f) - mu * mu;
        const float rs  = rsqrtf(var + 1e-5f);
        // write LN2 output into O_K (K is dead since phase 3; barrier passed at phase 4)
#pragma unroll
        for (int j = 0; j < 4; ++j) {
            bf16x8 pk;
#pragma unroll
            for (int e = 0; e < 8; ++e) {
                const int d = l4 * 32 + j * 8 + e;
                pk[e] = (__bf16)((vals[j*8+e] - mu) * rs * ln2g[d] + ln2b[d]);
            }
            const int byteOff = (l4 * 64 + j * 16) ^ ((row & 7) << 4);
            *reinterpret_cast<bf16x8*>(s_k + row * 256 + byteOff) = pk;
        }
    }
    __syncthreads();

    // ---------- phase 6/7: MLP (hidden split in 2 halves of 256) ----------
    bf16x8 a[4][4];
#pragma unroll
    for (int rt = 0; rt < 4; ++rt)
#pragma unroll
        for (int kc = 0; kc < 4; ++kc)
            a[rt][kc] = lds_frag(s_k, rt * 16 + ar, kc * 64 + (kg << 4), 256);

    f32x4 acc2[2][4];
#pragma unroll
    for (int ct2 = 0; ct2 < 2; ++ct2) {
        const float bb = b2[(w + ct2 * 4) * 16 + ar];
#pragma unroll
        for (int rt = 0; rt < 4; ++rt) acc2[ct2][rt] = {bb, bb, bb, bb};
    }

#pragma unroll
    for (int hh = 0; hh < 2; ++hh) {
        // GEMM1 half: gelu(xn2 @ w1) -> s_h
#pragma unroll
        for (int i = 0; i < 4; ++i) {
            const int ct = hh * 16 + w + 4 * i;
            const int brow = ct * 16 + ar;          // hidden col
            bf16x8 bfr[4];
#pragma unroll
            for (int kc = 0; kc < 4; ++kc)
                bfr[kc] = *reinterpret_cast<const bf16x8*>(w1T + brow * 128 + kc * 32 + (kg << 3));
            const float bb = b1[brow];
#pragma unroll
            for (int rt = 0; rt < 4; ++rt) {
                f32x4 c = {bb, bb, bb, bb};
#pragma unroll
                for (int kc = 0; kc < 4; ++kc)
                    c = __builtin_amdgcn_mfma_f32_16x16x32_bf16(a[rt][kc], bfr[kc], c, 0, 0, 0);
#pragma unroll
                for (int r = 0; r < 4; ++r) {
                    const float v = c[r];
                    const float t = 0.7978845608028654f * (v + 0.044715f * v * v * v);
                    const float th = 1.f - 2.f / (__expf(2.f * t) + 1.f);
                    lds_wr_bf16(s_h, rt * 16 + kg * 4 + r, brow - hh * 256, 512, 0.5f * v * (1.f + th));
                }
            }
        }
        __syncthreads();
        // GEMM2 partial: y += h_half @ w2[hh*256..]
#pragma unroll
        for (int kc = 0; kc < 8; ++kc) {
            bf16x8 ah[4];
#pragma unroll
            for (int rt = 0; rt < 4; ++rt)
                ah[rt] = lds_frag(s_h, rt * 16 + ar, kc * 64 + (kg << 4), 512);
#pragma unroll
            for (int ct2 = 0; ct2 < 2; ++ct2) {
                const int brow = (w + ct2 * 4) * 16 + ar;
                const bf16x8 bw = *reinterpret_cast<const bf16x8*>(w2T + brow * 512 + hh * 256 + kc * 32 + (kg << 3));
#pragma unroll
                for (int rt = 0; rt < 4; ++rt)
                    acc2[ct2][rt] = __builtin_amdgcn_mfma_f32_16x16x32_bf16(ah[rt], bw, acc2[ct2][rt], 0, 0, 0);
            }
        }
        __syncthreads();
    }

    // ---------- phase 8: stage MLP out (f32 [64][132] @ smem+0), final write ----------
#pragma unroll
    for (int ct2 = 0; ct2 < 2; ++ct2)
#pragma unroll
        for (int rt = 0; rt < 4; ++rt)
#pragma unroll
            for (int r = 0; r < 4; ++r)
                s_out[(rt * 16 + kg * 4 + r) * 132 + (w + ct2 * 4) * 16 + ar] = acc2[ct2][rt][r];
    __syncthreads();
    {
        const int base = s_base[row];
        float* op = out + base + l4 * 32;
        const float* po = s_out + row * 132 + l4 * 32;
#pragma unroll
        for (int i = 0; i < 8; ++i) {
            float4 o;
            o.x = vals[4*i+0] + po[4*i+0];
            o.y = vals[4*i+1] + po[4*i+1];
            o.z = vals[4*i+2] + po[4*i+2];
            o.w = vals[4*i+3] + po[4*i+3];
            reinterpret_cast<float4*>(op)[i] = o;
        }
    }
}

extern "C" void kernel_launch(void* const* d_in, const int* in_sizes, int n_in,
                              void* d_out, int out_size, void* d_ws, size_t ws_size,
                              hipStream_t stream) {
    (void)in_sizes; (void)n_in; (void)ws_size; (void)out_size;
    const float* x    = (const float*)d_in[0];
    const float* wq   = (const float*)d_in[1];
    const float* bq   = (const float*)d_in[2];
    const float* wk   = (const float*)d_in[3];
    const float* bk   = (const float*)d_in[4];
    const float* wv   = (const float*)d_in[5];
    const float* bv   = (const float*)d_in[6];
    const float* wp   = (const float*)d_in[7];
    const float* bp   = (const float*)d_in[8];
    const float* rpb  = (const float*)d_in[9];
    const float* ln1g = (const float*)d_in[10];
    const float* ln1b = (const float*)d_in[11];
    const float* ln2g = (const float*)d_in[12];
    const float* ln2b = (const float*)d_in[13];
    const float* w1   = (const float*)d_in[14];
    const float* b1   = (const float*)d_in[15];
    const float* w2   = (const float*)d_in[16];
    const float* b2   = (const float*)d_in[17];
    const float* gate = (const float*)d_in[18];
    float* out = (float*)d_out;

    __bf16* ws = (__bf16*)d_ws;
    const __bf16* wqT = ws;
    const __bf16* wkT = ws + 16384;
    const __bf16* wvT = ws + 32768;
    const __bf16* wpT = ws + 49152;
    const __bf16* w1T = ws + 65536;
    const __bf16* w2T = ws + 131072;
    const float* wsf  = (const float*)(ws + 196608);
    const float* bias_pre = wsf;
    const float* bqs      = wsf + 8192;

    convert_w<<<801, 256, 0, stream>>>(wq, wk, wv, wp, w1, w2, rpb, bq, ws);
    swin_fused_kernel<<<8192, TPB, 0, stream>>>(x, wqT, wkT, bk, wvT, bv, wpT, bp,
                                                bias_pre, bqs, ln1g, ln1b, ln2g, ln2b,
                                                w1T, b1, w2T, b2, gate, out);
}